// Round 16
// baseline (172.310 us; speedup 1.0000x reference)
//
#include <hip/hip_runtime.h>

#define NN 20000
#define EE 320000

typedef unsigned int  u32;
typedef unsigned short u16;

typedef _Float16 h8 __attribute__((ext_vector_type(8)));
typedef _Float16 h2 __attribute__((ext_vector_type(2)));
typedef float    f4 __attribute__((ext_vector_type(4)));

union U16 { uint4 u; h8 h; };

__device__ inline u32 phh(float a, float b){
  h2 v; v[0] = (_Float16)a; v[1] = (_Float16)b;
  return __builtin_bit_cast(u32, v);
}
__device__ inline u16 f2h_u(float a){
  _Float16 h = (_Float16)a;
  return __builtin_bit_cast(u16, h);
}
__device__ inline float2 up2(u32 u){
  h2 v = __builtin_bit_cast(h2, u);
  return make_float2((float)v[0], (float)v[1]);
}
__device__ inline h8 pack8(float4 a, float4 b){
  U16 t;
  t.u.x = phh(a.x, a.y);
  t.u.y = phh(a.z, a.w);
  t.u.z = phh(b.x, b.y);
  t.u.w = phh(b.z, b.w);
  return t.h;
}

// ---------------------------------------------------------------------------
// k0: pack all weights into MFMA fragment order, f16.
// Frag layout (16x16x32): lane holds M[k=(lane/16)*8+j][c=ct*16+lane%16].
// ws (u16 units):
//   [0,65536)        W2pack: [d][ct(8)][ks(4)][lane(64)][j(8)]  (c 0-63=Wq, 64-127=Wk[d])
//   [65536,73728)    mw1pack: [ct(8)][ks(2)][lane][j]   (K=64)
//   [73728,90112)    mw2pack
//   [90112,106496)   mt1pack
//   [106496,122880)  mt2pack
// ---------------------------------------------------------------------------
__global__ void k0_pack(const float* __restrict__ Wq, const float* __restrict__ Wk,
                        const float* __restrict__ w1w, const float* __restrict__ w2w,
                        const float* __restrict__ w1t, const float* __restrict__ w2t,
                        u16* __restrict__ pack)
{
  const int tot = 65536 + 8192 + 16384*3;
  for (int o = blockIdx.x*blockDim.x + threadIdx.x; o < tot; o += gridDim.x*blockDim.x){
    float v;
    if (o < 65536){
      int d = o >> 14, r = o & 16383;
      int ct = r >> 11, ks = (r >> 9) & 3, lane = (r >> 3) & 63, j = r & 7;
      int k = ks*32 + (lane >> 4)*8 + j, c = ct*16 + (lane & 15);
      v = (c < 64) ? Wq[k*64 + c] : Wk[((d << 7) + k)*64 + (c - 64)];
    } else if (o < 73728){
      int r = o - 65536;
      int ct = r >> 10, ks = (r >> 9) & 1, lane = (r >> 3) & 63, j = r & 7;
      int k = ks*32 + (lane >> 4)*8 + j, c = ct*16 + (lane & 15);
      v = w1w[k*128 + c];
    } else {
      int r = o - 73728;
      int m = r >> 14; r &= 16383;
      int ct = r >> 11, ks = (r >> 9) & 3, lane = (r >> 3) & 63, j = r & 7;
      int k = ks*32 + (lane >> 4)*8 + j, c = ct*16 + (lane & 15);
      const float* M = (m == 0) ? w2w : (m == 1) ? w1t : w2t;
      v = M[k*128 + c];
    }
    pack[o] = f2h_u(v);
  }
}

// ---------------------------------------------------------------------------
// k1: per-d projection GEMM: [N x 128] @ [128 x 128] -> q||k per node, f16.
// ---------------------------------------------------------------------------
__global__ __launch_bounds__(256) void k1_proj(const float* __restrict__ X,
    const u16* __restrict__ wpack, u16* __restrict__ Q, u16* __restrict__ Kv)
{
  const int d = blockIdx.y;
  const int nBase = blockIdx.x * 64;
  const int wv = threadIdx.x >> 6;
  const int l  = threadIdx.x & 63;
  const int row16 = l & 15, g = l >> 4;
  int node_a = nBase + wv*16 + row16;
  int na = node_a < NN ? node_a : NN-1;          // clamp; stores are guarded
  const float* xrow = X + ((size_t)d*NN + na)*128;
  h8 a[4];
  #pragma unroll
  for (int ks = 0; ks < 4; ks++){
    float4 f0 = *(const float4*)(xrow + ks*32 + g*8);
    float4 f1 = *(const float4*)(xrow + ks*32 + g*8 + 4);
    a[ks] = pack8(f0, f1);
  }
  const uint4* wp4 = (const uint4*)wpack;
  #pragma unroll
  for (int ct = 0; ct < 8; ct++){
    f4 acc = {0.f, 0.f, 0.f, 0.f};
    #pragma unroll
    for (int ks = 0; ks < 4; ks++){
      U16 b; b.u = wp4[((d*8 + ct)*4 + ks)*64 + l];
      acc = __builtin_amdgcn_mfma_f32_16x16x32_f16(a[ks], b.h, acc, 0, 0, 0);
    }
    u16* dst = (ct < 4) ? Q : Kv;
    int cc = (ct & 3)*16 + row16;
    #pragma unroll
    for (int r = 0; r < 4; r++){
      int node = nBase + wv*16 + g*4 + r;        // D: col=lane&15, row=(lane>>4)*4+r
      if (node < NN) dst[(size_t)node*256 + d*64 + cc] = f2h_u(acc[r]);
    }
  }
}

// ---------------------------------------------------------------------------
// kA: gather + edge dot -> w_ij f16 [E][64] in ws. (R8-validated)
// ---------------------------------------------------------------------------
__global__ __launch_bounds__(256) void kA_dot(
    const u16* __restrict__ Q, const u16* __restrict__ Kv,
    const int* __restrict__ eidx, u16* __restrict__ Wg)
{
  const int wv = threadIdx.x >> 6;
  const int l  = threadIdx.x & 63;
  const int eBase = (blockIdx.x*4 + wv)*16;
  const int er = l >> 2, p = l & 3;
  const int eg = eBase + er;
  const int nj = eidx[eg];        // edge_index[0] = n_j (sender, uses ek)
  const int ni = eidx[EE + eg];   // edge_index[1] = n_i (receiver, uses eq)
  const u16* qb = Q  + (size_t)ni*256 + p*16;
  const u16* kb = Kv + (size_t)nj*256 + p*16;
  float acc16[16];
  #pragma unroll
  for (int j = 0; j < 16; j++) acc16[j] = 0.f;
  #pragma unroll
  for (int dd = 0; dd < 4; dd++){
    uint4 qa = *(const uint4*)(qb + dd*64);
    uint4 qc = *(const uint4*)(qb + dd*64 + 8);
    uint4 ka = *(const uint4*)(kb + dd*64);
    uint4 kc = *(const uint4*)(kb + dd*64 + 8);
    u32 qs[8] = {qa.x,qa.y,qa.z,qa.w,qc.x,qc.y,qc.z,qc.w};
    u32 ks_[8] = {ka.x,ka.y,ka.z,ka.w,kc.x,kc.y,kc.z,kc.w};
    #pragma unroll
    for (int j = 0; j < 8; j++){
      float2 qf = up2(qs[j]), kf = up2(ks_[j]);
      acc16[2*j]   += qf.x * kf.x;
      acc16[2*j+1] += qf.y * kf.y;
    }
  }
  uint4 wlo, whi;
  wlo.x = phh(acc16[0],acc16[1]);   wlo.y = phh(acc16[2],acc16[3]);
  wlo.z = phh(acc16[4],acc16[5]);   wlo.w = phh(acc16[6],acc16[7]);
  whi.x = phh(acc16[8],acc16[9]);   whi.y = phh(acc16[10],acc16[11]);
  whi.z = phh(acc16[12],acc16[13]); whi.w = phh(acc16[14],acc16[15]);
  uint4* dst = (uint4*)(Wg + (size_t)eg*64 + p*16);
  dst[0] = wlo;
  dst[1] = whi;
}

// ---------------------------------------------------------------------------
// k2_mlp v12: persistent weights + 2-TILE WEIGHT SHARING via phase-split.
//  Per wave: a PAIR of 16-edge tiles. Output feats processed in two 64-wide
//  phases, so the hidden buffer is 2KB/tile -> both tiles fit the 4KB/wave hb.
//  Every weight ds_read_b128 feeds 2 MFMAs (tile0+tile1) -> LDS weight
//  traffic per edge HALVED (the dominant cost per R15 post-mortem).
//  L2-stage accs stay f32 across phases (accT/accY); same 512-thr geometry,
//  LDS 146KB, launch_bounds(512,2) -> VGPR cap 256 (est. ~200 live).
// ---------------------------------------------------------------------------
#define MW1_4 0
#define MW2_4 1024
#define MT1_4 3072
#define MT2_4 5120

#define K2_LOAD2(T00,T01,T02,T03,T10,T11,T12,T13,PAIR)                          \
{                                                                               \
  const float* t0_ = T + (size_t)((PAIR)*32 + e16)*128;                         \
  const float* t1_ = t0_ + 2048;                                                \
  float4 a_, b_;                                                                \
  a_ = *(const float4*)(t0_ +  0 + g*8); b_ = *(const float4*)(t0_ +  0 + g*8 + 4); T00 = pack8(a_,b_); \
  a_ = *(const float4*)(t0_ + 32 + g*8); b_ = *(const float4*)(t0_ + 32 + g*8 + 4); T01 = pack8(a_,b_); \
  a_ = *(const float4*)(t0_ + 64 + g*8); b_ = *(const float4*)(t0_ + 64 + g*8 + 4); T02 = pack8(a_,b_); \
  a_ = *(const float4*)(t0_ + 96 + g*8); b_ = *(const float4*)(t0_ + 96 + g*8 + 4); T03 = pack8(a_,b_); \
  a_ = *(const float4*)(t1_ +  0 + g*8); b_ = *(const float4*)(t1_ +  0 + g*8 + 4); T10 = pack8(a_,b_); \
  a_ = *(const float4*)(t1_ + 32 + g*8); b_ = *(const float4*)(t1_ + 32 + g*8 + 4); T11 = pack8(a_,b_); \
  a_ = *(const float4*)(t1_ + 64 + g*8); b_ = *(const float4*)(t1_ + 64 + g*8 + 4); T12 = pack8(a_,b_); \
  a_ = *(const float4*)(t1_ + 96 + g*8); b_ = *(const float4*)(t1_ + 96 + g*8 + 4); T13 = pack8(a_,b_); \
}

// one 64-feat output phase of the t-chain (both tiles)
#define T_PHASE(PH,T00,T01,T02,T03,T10,T11,T12,T13)                             \
{                                                                               \
  _Pragma("unroll")                                                             \
  for (int c4 = 0; c4 < 4; c4++){                                               \
    const int ct = (PH)*4 + c4;                                                 \
    U16 q0,q1,q2,q3;                                                            \
    q0.u = wlds4[MT1_4 + (ct*4+0)*64 + l];                                      \
    q1.u = wlds4[MT1_4 + (ct*4+1)*64 + l];                                      \
    q2.u = wlds4[MT1_4 + (ct*4+2)*64 + l];                                      \
    q3.u = wlds4[MT1_4 + (ct*4+3)*64 + l];                                      \
    f4 A0 = {0.f,0.f,0.f,0.f}, A1 = A0;                                         \
    __builtin_amdgcn_s_setprio(1);                                              \
    A0 = __builtin_amdgcn_mfma_f32_16x16x32_f16(q0.h, T00, A0, 0, 0, 0);        \
    A1 = __builtin_amdgcn_mfma_f32_16x16x32_f16(q0.h, T10, A1, 0, 0, 0);        \
    A0 = __builtin_amdgcn_mfma_f32_16x16x32_f16(q1.h, T01, A0, 0, 0, 0);        \
    A1 = __builtin_amdgcn_mfma_f32_16x16x32_f16(q1.h, T11, A1, 0, 0, 0);        \
    A0 = __builtin_amdgcn_mfma_f32_16x16x32_f16(q2.h, T02, A0, 0, 0, 0);        \
    A1 = __builtin_amdgcn_mfma_f32_16x16x32_f16(q2.h, T12, A1, 0, 0, 0);        \
    A0 = __builtin_amdgcn_mfma_f32_16x16x32_f16(q3.h, T03, A0, 0, 0, 0);        \
    A1 = __builtin_amdgcn_mfma_f32_16x16x32_f16(q3.h, T13, A1, 0, 0, 0);        \
    __builtin_amdgcn_s_setprio(0);                                              \
    float4 bb = *(const float4*)&bias_lds[256 + ct*16 + g*4];                   \
    const int hi = e16*64 + ((c4*16 + g*4) ^ swz);                              \
    uint2 v;                                                                    \
    v.x = phh(fmaxf(A0[0]+bb.x,0.f), fmaxf(A0[1]+bb.y,0.f));                    \
    v.y = phh(fmaxf(A0[2]+bb.z,0.f), fmaxf(A0[3]+bb.w,0.f));                    \
    *(uint2*)&hb0[hi] = v;                                                      \
    v.x = phh(fmaxf(A1[0]+bb.x,0.f), fmaxf(A1[1]+bb.y,0.f));                    \
    v.y = phh(fmaxf(A1[2]+bb.z,0.f), fmaxf(A1[3]+bb.w,0.f));                    \
    *(uint2*)&hb1[hi] = v;                                                      \
  }                                                                             \
  U16 h00,h01,h10,h11;                                                          \
  h00.u = *(const uint4*)&hb0[e16*64 + (( 0 + g*8) ^ swz)];                     \
  h01.u = *(const uint4*)&hb0[e16*64 + ((32 + g*8) ^ swz)];                     \
  h10.u = *(const uint4*)&hb1[e16*64 + (( 0 + g*8) ^ swz)];                     \
  h11.u = *(const uint4*)&hb1[e16*64 + ((32 + g*8) ^ swz)];                     \
  _Pragma("unroll")                                                             \
  for (int ct = 0; ct < 8; ct++){                                               \
    U16 q0,q1;                                                                  \
    q0.u = wlds4[MT2_4 + (ct*4 + (PH)*2 + 0)*64 + l];                           \
    q1.u = wlds4[MT2_4 + (ct*4 + (PH)*2 + 1)*64 + l];                           \
    __builtin_amdgcn_s_setprio(1);                                              \
    accT0[ct] = __builtin_amdgcn_mfma_f32_16x16x32_f16(q0.h, h00.h, accT0[ct], 0, 0, 0); \
    accT1[ct] = __builtin_amdgcn_mfma_f32_16x16x32_f16(q0.h, h10.h, accT1[ct], 0, 0, 0); \
    accT0[ct] = __builtin_amdgcn_mfma_f32_16x16x32_f16(q1.h, h01.h, accT0[ct], 0, 0, 0); \
    accT1[ct] = __builtin_amdgcn_mfma_f32_16x16x32_f16(q1.h, h11.h, accT1[ct], 0, 0, 0); \
    __builtin_amdgcn_s_setprio(0);                                              \
  }                                                                             \
}

// one 64-feat output phase of the w-chain (both tiles)
#define W_PHASE(PH)                                                             \
{                                                                               \
  _Pragma("unroll")                                                             \
  for (int c4 = 0; c4 < 4; c4++){                                               \
    const int ct = (PH)*4 + c4;                                                 \
    U16 q0,q1;                                                                  \
    q0.u = wlds4[MW1_4 + (ct*2+0)*64 + l];                                      \
    q1.u = wlds4[MW1_4 + (ct*2+1)*64 + l];                                      \
    f4 B0 = {0.f,0.f,0.f,0.f}, B1 = B0;                                         \
    __builtin_amdgcn_s_setprio(1);                                              \
    B0 = __builtin_amdgcn_mfma_f32_16x16x32_f16(q0.h, wf00.h, B0, 0, 0, 0);     \
    B1 = __builtin_amdgcn_mfma_f32_16x16x32_f16(q0.h, wf10.h, B1, 0, 0, 0);     \
    B0 = __builtin_amdgcn_mfma_f32_16x16x32_f16(q1.h, wf01.h, B0, 0, 0, 0);     \
    B1 = __builtin_amdgcn_mfma_f32_16x16x32_f16(q1.h, wf11.h, B1, 0, 0, 0);     \
    __builtin_amdgcn_s_setprio(0);                                              \
    float4 bb = *(const float4*)&bias_lds[0 + ct*16 + g*4];                     \
    const int hi = e16*64 + ((c4*16 + g*4) ^ swz);                              \
    uint2 v;                                                                    \
    v.x = phh(fmaxf(B0[0]+bb.x,0.f), fmaxf(B0[1]+bb.y,0.f));                    \
    v.y = phh(fmaxf(B0[2]+bb.z,0.f), fmaxf(B0[3]+bb.w,0.f));                    \
    *(uint2*)&hb0[hi] = v;                                                      \
    v.x = phh(fmaxf(B1[0]+bb.x,0.f), fmaxf(B1[1]+bb.y,0.f));                    \
    v.y = phh(fmaxf(B1[2]+bb.z,0.f), fmaxf(B1[3]+bb.w,0.f));                    \
    *(uint2*)&hb1[hi] = v;                                                      \
  }                                                                             \
  U16 h00,h01,h10,h11;                                                          \
  h00.u = *(const uint4*)&hb0[e16*64 + (( 0 + g*8) ^ swz)];                     \
  h01.u = *(const uint4*)&hb0[e16*64 + ((32 + g*8) ^ swz)];                     \
  h10.u = *(const uint4*)&hb1[e16*64 + (( 0 + g*8) ^ swz)];                     \
  h11.u = *(const uint4*)&hb1[e16*64 + ((32 + g*8) ^ swz)];                     \
  _Pragma("unroll")                                                             \
  for (int ct = 0; ct < 8; ct++){                                               \
    U16 q0,q1;                                                                  \
    q0.u = wlds4[MW2_4 + (ct*4 + (PH)*2 + 0)*64 + l];                           \
    q1.u = wlds4[MW2_4 + (ct*4 + (PH)*2 + 1)*64 + l];                           \
    __builtin_amdgcn_s_setprio(1);                                              \
    accY0[ct] = __builtin_amdgcn_mfma_f32_16x16x32_f16(q0.h, h00.h, accY0[ct], 0, 0, 0); \
    accY1[ct] = __builtin_amdgcn_mfma_f32_16x16x32_f16(q0.h, h10.h, accY1[ct], 0, 0, 0); \
    accY0[ct] = __builtin_amdgcn_mfma_f32_16x16x32_f16(q1.h, h01.h, accY0[ct], 0, 0, 0); \
    accY1[ct] = __builtin_amdgcn_mfma_f32_16x16x32_f16(q1.h, h11.h, accY1[ct], 0, 0, 0); \
    __builtin_amdgcn_s_setprio(0);                                              \
  }                                                                             \
}

#define K2_TILE2(T00,T01,T02,T03,T10,T11,T12,T13,PAIR)                          \
{                                                                               \
  U16 wf00,wf01,wf10,wf11;                                                      \
  { const uint4* w0_ = (const uint4*)(Wg + (size_t)((PAIR)*32 + e16)*64);       \
    const uint4* w1_ = (const uint4*)(Wg + (size_t)((PAIR)*32 + 16 + e16)*64);  \
    wf00.u = w0_[g]; wf01.u = w0_[4+g];                                         \
    wf10.u = w1_[g]; wf11.u = w1_[4+g]; }                                       \
  f4 accT0[8], accT1[8];                                                        \
  _Pragma("unroll")                                                             \
  for (int ct = 0; ct < 8; ct++){                                               \
    accT0[ct] = (f4){0.f,0.f,0.f,0.f};                                          \
    accT1[ct] = (f4){0.f,0.f,0.f,0.f};                                          \
  }                                                                             \
  T_PHASE(0,T00,T01,T02,T03,T10,T11,T12,T13)                                    \
  T_PHASE(1,T00,T01,T02,T03,T10,T11,T12,T13)                                    \
  uint2 aT0[8], aT1[8];                                                         \
  _Pragma("unroll")                                                             \
  for (int ct = 0; ct < 8; ct++){                                               \
    float4 bb = *(const float4*)&bias_lds[384 + ct*16 + g*4];                   \
    aT0[ct].x = phh(accT0[ct][0]+bb.x, accT0[ct][1]+bb.y);                      \
    aT0[ct].y = phh(accT0[ct][2]+bb.z, accT0[ct][3]+bb.w);                      \
    aT1[ct].x = phh(accT1[ct][0]+bb.x, accT1[ct][1]+bb.y);                      \
    aT1[ct].y = phh(accT1[ct][2]+bb.z, accT1[ct][3]+bb.w);                      \
  }                                                                             \
  f4 accY0[8], accY1[8];                                                        \
  _Pragma("unroll")                                                             \
  for (int ct = 0; ct < 8; ct++){                                               \
    accY0[ct] = (f4){0.f,0.f,0.f,0.f};                                          \
    accY1[ct] = (f4){0.f,0.f,0.f,0.f};                                          \
  }                                                                             \
  W_PHASE(0)                                                                    \
  W_PHASE(1)                                                                    \
  _Pragma("unroll")                                                             \
  for (int ct = 0; ct < 8; ct++){                                               \
    float4 bb = *(const float4*)&bias_lds[128 + ct*16 + g*4];                   \
    float2 tl0 = up2(aT0[ct].x), th0 = up2(aT0[ct].y);                          \
    float4 o;                                                                   \
    o.x = (accY0[ct][0]+bb.x)*tl0.x;                                            \
    o.y = (accY0[ct][1]+bb.y)*tl0.y;                                            \
    o.z = (accY0[ct][2]+bb.z)*th0.x;                                            \
    o.w = (accY0[ct][3]+bb.w)*th0.y;                                            \
    *(float4*)&out[(size_t)((PAIR)*32 + e16)*128 + ct*16 + g*4] = o;            \
    float2 tl1 = up2(aT1[ct].x), th1 = up2(aT1[ct].y);                          \
    o.x = (accY1[ct][0]+bb.x)*tl1.x;                                            \
    o.y = (accY1[ct][1]+bb.y)*tl1.y;                                            \
    o.z = (accY1[ct][2]+bb.z)*th1.x;                                            \
    o.w = (accY1[ct][3]+bb.w)*th1.y;                                            \
    *(float4*)&out[(size_t)((PAIR)*32 + 16 + e16)*128 + ct*16 + g*4] = o;       \
  }                                                                             \
}

__global__ __launch_bounds__(512, 2) void k2_mlp(
    const u16* __restrict__ Wg, const float* __restrict__ T,
    const u16* __restrict__ wsrc,           // pack + 65536 (mw1,mw2,mt1,mt2 linear)
    const float* __restrict__ b1w, const float* __restrict__ b2w,
    const float* __restrict__ b1t, const float* __restrict__ b2t,
    float* __restrict__ out, int nPairs)
{
  __shared__ alignas(16) u16   wlds[57344];    // 112KB packed MLP weights
  __shared__ alignas(16) float bias_lds[512];  // b1w|b2w|b1t|b2t
  __shared__ alignas(16) u16   hb[8][2048];    // 4KB/wave: 2KB per tile of pair
  {
    const uint4* src = (const uint4*)wsrc;
    uint4* dst = (uint4*)wlds;
    #pragma unroll
    for (int i = 0; i < 14; i++)
      dst[threadIdx.x + i*512] = src[threadIdx.x + i*512];
    int t = threadIdx.x;
    float bv = (t < 128) ? b1w[t] : (t < 256) ? b2w[t-128]
             : (t < 384) ? b1t[t-256] : b2t[t-384];
    bias_lds[t] = bv;
  }
  __syncthreads();                             // only barrier in the kernel

  const int wv = threadIdx.x >> 6;
  const int l  = threadIdx.x & 63;
  const int e16 = l & 15, g = l >> 4;
  const int swz = (e16 & 7) << 3;
  const uint4* wlds4 = (const uint4*)wlds;
  u16* hb0 = hb[wv];
  u16* hb1 = hb[wv] + 1024;
  const int pStride = gridDim.x << 3;

  h8 tA00,tA01,tA02,tA03,tA10,tA11,tA12,tA13;
  h8 tB00,tB01,tB02,tB03,tB10,tB11,tB12,tB13;

  int p = blockIdx.x*8 + wv;                   // pair index; nPairs = EE/32
  K2_LOAD2(tA00,tA01,tA02,tA03,tA10,tA11,tA12,tA13,p)
  while (true){
    int pn = p + pStride;
    bool v1 = pn < nPairs;
    if (v1) { K2_LOAD2(tB00,tB01,tB02,tB03,tB10,tB11,tB12,tB13,pn) }
    K2_TILE2(tA00,tA01,tA02,tA03,tA10,tA11,tA12,tA13,p)
    if (!v1) return;
    int pn2 = pn + pStride;
    bool v2 = pn2 < nPairs;
    if (v2) { K2_LOAD2(tA00,tA01,tA02,tA03,tA10,tA11,tA12,tA13,pn2) }
    K2_TILE2(tB00,tB01,tB02,tB03,tB10,tB11,tB12,tB13,pn)
    if (!v2) return;
    p = pn2;
  }
}

extern "C" void kernel_launch(void* const* d_in, const int* in_sizes, int n_in,
                              void* d_out, int out_size, void* d_ws, size_t ws_size,
                              hipStream_t stream) {
  const float* X   = (const float*)d_in[0];
  const float* T   = (const float*)d_in[1];
  const int*   EI  = (const int*)  d_in[2];
  const float* Wq  = (const float*)d_in[3];
  const float* Wk  = (const float*)d_in[4];
  const float* w1w = (const float*)d_in[5];
  const float* b1w = (const float*)d_in[6];
  const float* w2w = (const float*)d_in[7];
  const float* b2w = (const float*)d_in[8];
  const float* w1t = (const float*)d_in[9];
  const float* b1t = (const float*)d_in[10];
  const float* w2t = (const float*)d_in[11];
  const float* b2t = (const float*)d_in[12];
  float* out = (float*)d_out;

  u16* ws   = (u16*)d_ws;
  u16* pack = ws;                           // 240 KB packed weights
  u16* Q    = ws + 122880;                  // [N][256] f16 (10.24 MB)
  u16* Kv   = Q + (size_t)NN*256;           // [N][256] f16 (10.24 MB)
  u16* Wg   = Kv + (size_t)NN*256;          // [E][64] f16  (40.96 MB)

  k0_pack<<<64, 256, 0, stream>>>(Wq, Wk, w1w, w2w, w1t, w2t, pack);
  k1_proj<<<dim3((NN + 63)/64, 4), 256, 0, stream>>>(X, pack, Q, Kv);
  kA_dot<<<EE/64, 256, 0, stream>>>(Q, Kv, EI, Wg);
  k2_mlp<<<256, 512, 0, stream>>>(Wg, T, (const u16*)(ws + 65536),
      b1w, b2w, b1t, b2t, out, EE/32);
}

// Round 17
// 145.270 us; speedup vs baseline: 1.1861x; 1.1861x over previous
//
#include <hip/hip_runtime.h>

#define NN 20000
#define EE 320000

typedef unsigned int  u32;
typedef unsigned short u16;

typedef _Float16 h8 __attribute__((ext_vector_type(8)));
typedef _Float16 h2 __attribute__((ext_vector_type(2)));
typedef float    f4 __attribute__((ext_vector_type(4)));

union U16 { uint4 u; h8 h; };

__device__ inline u32 phh(float a, float b){
  h2 v; v[0] = (_Float16)a; v[1] = (_Float16)b;
  return __builtin_bit_cast(u32, v);
}
__device__ inline u16 f2h_u(float a){
  _Float16 h = (_Float16)a;
  return __builtin_bit_cast(u16, h);
}
__device__ inline float2 up2(u32 u){
  h2 v = __builtin_bit_cast(h2, u);
  return make_float2((float)v[0], (float)v[1]);
}
__device__ inline h8 pack8(float4 a, float4 b){
  U16 t;
  t.u.x = phh(a.x, a.y);
  t.u.y = phh(a.z, a.w);
  t.u.z = phh(b.x, b.y);
  t.u.w = phh(b.z, b.w);
  return t.h;
}

// ---------------------------------------------------------------------------
// k0: pack all weights into MFMA fragment order, f16.
// Frag layout (16x16x32): lane holds M[k=(lane/16)*8+j][c=ct*16+lane%16].
// ws (u16 units):
//   [0,65536)        W2pack: [d][ct(8)][ks(4)][lane(64)][j(8)]  (c 0-63=Wq, 64-127=Wk[d])
//   [65536,73728)    mw1pack: [ct(8)][ks(2)][lane][j]   (K=64)
//   [73728,90112)    mw2pack
//   [90112,106496)   mt1pack
//   [106496,122880)  mt2pack
// ---------------------------------------------------------------------------
__global__ void k0_pack(const float* __restrict__ Wq, const float* __restrict__ Wk,
                        const float* __restrict__ w1w, const float* __restrict__ w2w,
                        const float* __restrict__ w1t, const float* __restrict__ w2t,
                        u16* __restrict__ pack)
{
  const int tot = 65536 + 8192 + 16384*3;
  for (int o = blockIdx.x*blockDim.x + threadIdx.x; o < tot; o += gridDim.x*blockDim.x){
    float v;
    if (o < 65536){
      int d = o >> 14, r = o & 16383;
      int ct = r >> 11, ks = (r >> 9) & 3, lane = (r >> 3) & 63, j = r & 7;
      int k = ks*32 + (lane >> 4)*8 + j, c = ct*16 + (lane & 15);
      v = (c < 64) ? Wq[k*64 + c] : Wk[((d << 7) + k)*64 + (c - 64)];
    } else if (o < 73728){
      int r = o - 65536;
      int ct = r >> 10, ks = (r >> 9) & 1, lane = (r >> 3) & 63, j = r & 7;
      int k = ks*32 + (lane >> 4)*8 + j, c = ct*16 + (lane & 15);
      v = w1w[k*128 + c];
    } else {
      int r = o - 73728;
      int m = r >> 14; r &= 16383;
      int ct = r >> 11, ks = (r >> 9) & 3, lane = (r >> 3) & 63, j = r & 7;
      int k = ks*32 + (lane >> 4)*8 + j, c = ct*16 + (lane & 15);
      const float* M = (m == 0) ? w2w : (m == 1) ? w1t : w2t;
      v = M[k*128 + c];
    }
    pack[o] = f2h_u(v);
  }
}

// ---------------------------------------------------------------------------
// k1: per-d projection GEMM: [N x 128] @ [128 x 128] -> q||k per node, f16.
// ---------------------------------------------------------------------------
__global__ __launch_bounds__(256) void k1_proj(const float* __restrict__ X,
    const u16* __restrict__ wpack, u16* __restrict__ Q, u16* __restrict__ Kv)
{
  const int d = blockIdx.y;
  const int nBase = blockIdx.x * 64;
  const int wv = threadIdx.x >> 6;
  const int l  = threadIdx.x & 63;
  const int row16 = l & 15, g = l >> 4;
  int node_a = nBase + wv*16 + row16;
  int na = node_a < NN ? node_a : NN-1;          // clamp; stores are guarded
  const float* xrow = X + ((size_t)d*NN + na)*128;
  h8 a[4];
  #pragma unroll
  for (int ks = 0; ks < 4; ks++){
    float4 f0 = *(const float4*)(xrow + ks*32 + g*8);
    float4 f1 = *(const float4*)(xrow + ks*32 + g*8 + 4);
    a[ks] = pack8(f0, f1);
  }
  const uint4* wp4 = (const uint4*)wpack;
  #pragma unroll
  for (int ct = 0; ct < 8; ct++){
    f4 acc = {0.f, 0.f, 0.f, 0.f};
    #pragma unroll
    for (int ks = 0; ks < 4; ks++){
      U16 b; b.u = wp4[((d*8 + ct)*4 + ks)*64 + l];
      acc = __builtin_amdgcn_mfma_f32_16x16x32_f16(a[ks], b.h, acc, 0, 0, 0);
    }
    u16* dst = (ct < 4) ? Q : Kv;
    int cc = (ct & 3)*16 + row16;
    #pragma unroll
    for (int r = 0; r < 4; r++){
      int node = nBase + wv*16 + g*4 + r;        // D: col=lane&15, row=(lane>>4)*4+r
      if (node < NN) dst[(size_t)node*256 + d*64 + cc] = f2h_u(acc[r]);
    }
  }
}

// ---------------------------------------------------------------------------
// kA: gather + edge dot -> w_ij f16 [E][64] in ws. (R8-validated)
// L3-BW bound: 327MB gather traffic at ~8 TB/s ≈ its 40us duration.
// ---------------------------------------------------------------------------
__global__ __launch_bounds__(256) void kA_dot(
    const u16* __restrict__ Q, const u16* __restrict__ Kv,
    const int* __restrict__ eidx, u16* __restrict__ Wg)
{
  const int wv = threadIdx.x >> 6;
  const int l  = threadIdx.x & 63;
  const int eBase = (blockIdx.x*4 + wv)*16;
  const int er = l >> 2, p = l & 3;
  const int eg = eBase + er;
  const int nj = eidx[eg];        // edge_index[0] = n_j (sender, uses ek)
  const int ni = eidx[EE + eg];   // edge_index[1] = n_i (receiver, uses eq)
  const u16* qb = Q  + (size_t)ni*256 + p*16;
  const u16* kb = Kv + (size_t)nj*256 + p*16;
  float acc16[16];
  #pragma unroll
  for (int j = 0; j < 16; j++) acc16[j] = 0.f;
  #pragma unroll
  for (int dd = 0; dd < 4; dd++){
    uint4 qa = *(const uint4*)(qb + dd*64);
    uint4 qc = *(const uint4*)(qb + dd*64 + 8);
    uint4 ka = *(const uint4*)(kb + dd*64);
    uint4 kc = *(const uint4*)(kb + dd*64 + 8);
    u32 qs[8] = {qa.x,qa.y,qa.z,qa.w,qc.x,qc.y,qc.z,qc.w};
    u32 ks_[8] = {ka.x,ka.y,ka.z,ka.w,kc.x,kc.y,kc.z,kc.w};
    #pragma unroll
    for (int j = 0; j < 8; j++){
      float2 qf = up2(qs[j]), kf = up2(ks_[j]);
      acc16[2*j]   += qf.x * kf.x;
      acc16[2*j+1] += qf.y * kf.y;
    }
  }
  uint4 wlo, whi;
  wlo.x = phh(acc16[0],acc16[1]);   wlo.y = phh(acc16[2],acc16[3]);
  wlo.z = phh(acc16[4],acc16[5]);   wlo.w = phh(acc16[6],acc16[7]);
  whi.x = phh(acc16[8],acc16[9]);   whi.y = phh(acc16[10],acc16[11]);
  whi.z = phh(acc16[12],acc16[13]); whi.w = phh(acc16[14],acc16[15]);
  uint4* dst = (uint4*)(Wg + (size_t)eg*64 + p*16);
  dst[0] = wlo;
  dst[1] = whi;
}

// ---------------------------------------------------------------------------
// k2_mlp v11 (R15, best-known): 512 thr / 8 waves, 112KB weights + bias +
// 8x4KB hb in LDS, VGPR~128 no-spill; 2-way split accumulator chains +
// s_setprio around MFMA clusters; named-reg prefetch ping-pong.
// NOTE (R9-R16 lessons, do not revisit):
//  - blocks >8 waves: hipcc clamps VGPR (768->84, 960->64) -> spill
//  - multi-tile weight sharing: acc residency >~120 VGPR -> spill (R16)
//  - nontemporal hints on gfx950 = cache BYPASS (4x read amplification, R11)
//  - fusing kA's gather: T+out stream evicts Q/K from L3 -> HBM misses (R9)
// ---------------------------------------------------------------------------
#define MW1_4 0
#define MW2_4 1024
#define MT1_4 3072
#define MT2_4 5120

#define K2_LOAD(TF0,TF1,TF2,TF3,WF0,WF1,TIDX)                                   \
{                                                                               \
  const int e_ = (TIDX)*16 + e16;                                               \
  const float* trow_ = T + (size_t)e_*128;                                      \
  float4 a_, b_;                                                                \
  a_ = *(const float4*)(trow_ +  0 + g*8); b_ = *(const float4*)(trow_ +  0 + g*8 + 4); TF0 = pack8(a_,b_); \
  a_ = *(const float4*)(trow_ + 32 + g*8); b_ = *(const float4*)(trow_ + 32 + g*8 + 4); TF1 = pack8(a_,b_); \
  a_ = *(const float4*)(trow_ + 64 + g*8); b_ = *(const float4*)(trow_ + 64 + g*8 + 4); TF2 = pack8(a_,b_); \
  a_ = *(const float4*)(trow_ + 96 + g*8); b_ = *(const float4*)(trow_ + 96 + g*8 + 4); TF3 = pack8(a_,b_); \
  const uint4* wrow_ = (const uint4*)(Wg + (size_t)e_*64);                      \
  WF0.u = wrow_[g];                                                             \
  WF1.u = wrow_[4 + g];                                                         \
}

#define K2_TILE(TF0,TF1,TF2,TF3,WF0,WF1,TIDX)                                   \
{                                                                               \
  /* t-L1 -> hb (split acc chains) */                                           \
  _Pragma("unroll")                                                             \
  for (int ct = 0; ct < 8; ct++){                                               \
    U16 q0,q1,q2,q3;                                                            \
    q0.u = wlds4[MT1_4 + (ct*4+0)*64 + l];                                      \
    q1.u = wlds4[MT1_4 + (ct*4+1)*64 + l];                                      \
    q2.u = wlds4[MT1_4 + (ct*4+2)*64 + l];                                      \
    q3.u = wlds4[MT1_4 + (ct*4+3)*64 + l];                                      \
    f4 Aa = {0.f,0.f,0.f,0.f}, Ab = Aa;                                         \
    __builtin_amdgcn_s_setprio(1);                                              \
    Aa = __builtin_amdgcn_mfma_f32_16x16x32_f16(q0.h, TF0, Aa, 0, 0, 0);        \
    Ab = __builtin_amdgcn_mfma_f32_16x16x32_f16(q1.h, TF1, Ab, 0, 0, 0);        \
    Aa = __builtin_amdgcn_mfma_f32_16x16x32_f16(q2.h, TF2, Aa, 0, 0, 0);        \
    Ab = __builtin_amdgcn_mfma_f32_16x16x32_f16(q3.h, TF3, Ab, 0, 0, 0);        \
    __builtin_amdgcn_s_setprio(0);                                              \
    f4 A = Aa + Ab;                                                             \
    float4 bb = *(const float4*)&bias_lds[256 + ct*16 + g*4];                   \
    uint2 v;                                                                    \
    v.x = phh(fmaxf(A[0]+bb.x,0.f), fmaxf(A[1]+bb.y,0.f));                      \
    v.y = phh(fmaxf(A[2]+bb.z,0.f), fmaxf(A[3]+bb.w,0.f));                      \
    *(uint2*)&myhb[e16*128 + ((ct*16 + g*4) ^ swz)] = v;                        \
  }                                                                             \
  /* t-L2 -> accT (f16 packed, incl. b2t) */                                    \
  uint2 accT[8];                                                                \
  {                                                                             \
    U16 h0,h1,h2,h3;                                                            \
    h0.u = *(const uint4*)&myhb[e16*128 + (( 0 + g*8) ^ swz)];                  \
    h1.u = *(const uint4*)&myhb[e16*128 + ((32 + g*8) ^ swz)];                  \
    h2.u = *(const uint4*)&myhb[e16*128 + ((64 + g*8) ^ swz)];                  \
    h3.u = *(const uint4*)&myhb[e16*128 + ((96 + g*8) ^ swz)];                  \
    _Pragma("unroll")                                                           \
    for (int ct = 0; ct < 8; ct++){                                             \
      U16 q0,q1,q2,q3;                                                          \
      q0.u = wlds4[MT2_4 + (ct*4+0)*64 + l];                                    \
      q1.u = wlds4[MT2_4 + (ct*4+1)*64 + l];                                    \
      q2.u = wlds4[MT2_4 + (ct*4+2)*64 + l];                                    \
      q3.u = wlds4[MT2_4 + (ct*4+3)*64 + l];                                    \
      f4 Xa = {0.f,0.f,0.f,0.f}, Xb = Xa;                                       \
      __builtin_amdgcn_s_setprio(1);                                            \
      Xa = __builtin_amdgcn_mfma_f32_16x16x32_f16(q0.h, h0.h, Xa, 0, 0, 0);     \
      Xb = __builtin_amdgcn_mfma_f32_16x16x32_f16(q1.h, h1.h, Xb, 0, 0, 0);     \
      Xa = __builtin_amdgcn_mfma_f32_16x16x32_f16(q2.h, h2.h, Xa, 0, 0, 0);     \
      Xb = __builtin_amdgcn_mfma_f32_16x16x32_f16(q3.h, h3.h, Xb, 0, 0, 0);     \
      __builtin_amdgcn_s_setprio(0);                                            \
      f4 X = Xa + Xb;                                                           \
      float4 bb = *(const float4*)&bias_lds[384 + ct*16 + g*4];                 \
      accT[ct].x = phh(X[0]+bb.x, X[1]+bb.y);                                   \
      accT[ct].y = phh(X[2]+bb.z, X[3]+bb.w);                                   \
    }                                                                           \
  }                                                                             \
  /* w-L1 -> hb (reuse; same-wave DS in-order => WAR safe) */                   \
  _Pragma("unroll")                                                             \
  for (int ct = 0; ct < 8; ct++){                                               \
    U16 q0,q1;                                                                  \
    q0.u = wlds4[MW1_4 + (ct*2+0)*64 + l];                                      \
    q1.u = wlds4[MW1_4 + (ct*2+1)*64 + l];                                      \
    f4 Ba = {0.f,0.f,0.f,0.f}, Bb = Ba;                                         \
    __builtin_amdgcn_s_setprio(1);                                              \
    Ba = __builtin_amdgcn_mfma_f32_16x16x32_f16(q0.h, WF0.h, Ba, 0, 0, 0);      \
    Bb = __builtin_amdgcn_mfma_f32_16x16x32_f16(q1.h, WF1.h, Bb, 0, 0, 0);      \
    __builtin_amdgcn_s_setprio(0);                                              \
    f4 B = Ba + Bb;                                                             \
    float4 bb = *(const float4*)&bias_lds[0 + ct*16 + g*4];                     \
    uint2 v;                                                                    \
    v.x = phh(fmaxf(B[0]+bb.x,0.f), fmaxf(B[1]+bb.y,0.f));                      \
    v.y = phh(fmaxf(B[2]+bb.z,0.f), fmaxf(B[3]+bb.w,0.f));                      \
    *(uint2*)&myhb[e16*128 + ((ct*16 + g*4) ^ swz)] = v;                        \
  }                                                                             \
  /* w-L2 + fused epilogue */                                                   \
  {                                                                             \
    U16 h0,h1,h2,h3;                                                            \
    h0.u = *(const uint4*)&myhb[e16*128 + (( 0 + g*8) ^ swz)];                  \
    h1.u = *(const uint4*)&myhb[e16*128 + ((32 + g*8) ^ swz)];                  \
    h2.u = *(const uint4*)&myhb[e16*128 + ((64 + g*8) ^ swz)];                  \
    h3.u = *(const uint4*)&myhb[e16*128 + ((96 + g*8) ^ swz)];                  \
    _Pragma("unroll")                                                           \
    for (int ct = 0; ct < 8; ct++){                                             \
      U16 q0,q1,q2,q3;                                                          \
      q0.u = wlds4[MW2_4 + (ct*4+0)*64 + l];                                    \
      q1.u = wlds4[MW2_4 + (ct*4+1)*64 + l];                                    \
      q2.u = wlds4[MW2_4 + (ct*4+2)*64 + l];                                    \
      q3.u = wlds4[MW2_4 + (ct*4+3)*64 + l];                                    \
      f4 Ya = {0.f,0.f,0.f,0.f}, Yb = Ya;                                       \
      __builtin_amdgcn_s_setprio(1);                                            \
      Ya = __builtin_amdgcn_mfma_f32_16x16x32_f16(q0.h, h0.h, Ya, 0, 0, 0);     \
      Yb = __builtin_amdgcn_mfma_f32_16x16x32_f16(q1.h, h1.h, Yb, 0, 0, 0);     \
      Ya = __builtin_amdgcn_mfma_f32_16x16x32_f16(q2.h, h2.h, Ya, 0, 0, 0);     \
      Yb = __builtin_amdgcn_mfma_f32_16x16x32_f16(q3.h, h3.h, Yb, 0, 0, 0);     \
      __builtin_amdgcn_s_setprio(0);                                            \
      float4 bb = *(const float4*)&bias_lds[128 + ct*16 + g*4];                 \
      float2 tlo = up2(accT[ct].x), thi = up2(accT[ct].y);                      \
      float4 o;                                                                 \
      o.x = (Ya[0] + Yb[0] + bb.x) * tlo.x;                                     \
      o.y = (Ya[1] + Yb[1] + bb.y) * tlo.y;                                     \
      o.z = (Ya[2] + Yb[2] + bb.z) * thi.x;                                     \
      o.w = (Ya[3] + Yb[3] + bb.w) * thi.y;                                     \
      *(float4*)&out[(size_t)((TIDX)*16 + e16)*128 + ct*16 + g*4] = o;          \
    }                                                                           \
  }                                                                             \
}

__global__ __launch_bounds__(512, 2) void k2_mlp(
    const u16* __restrict__ Wg, const float* __restrict__ T,
    const u16* __restrict__ wsrc,           // pack + 65536 (mw1,mw2,mt1,mt2 linear)
    const float* __restrict__ b1w, const float* __restrict__ b2w,
    const float* __restrict__ b1t, const float* __restrict__ b2t,
    float* __restrict__ out, int nTiles)
{
  __shared__ alignas(16) u16   wlds[57344];    // 112KB packed MLP weights
  __shared__ alignas(16) float bias_lds[512];  // b1w|b2w|b1t|b2t
  __shared__ alignas(16) u16   hb[8][2048];    // 4KB hidden buffer per wave
  {
    const uint4* src = (const uint4*)wsrc;
    uint4* dst = (uint4*)wlds;
    #pragma unroll
    for (int i = 0; i < 14; i++)
      dst[threadIdx.x + i*512] = src[threadIdx.x + i*512];
    int t = threadIdx.x;
    float bv = (t < 128) ? b1w[t] : (t < 256) ? b2w[t-128]
             : (t < 384) ? b1t[t-256] : b2t[t-384];
    bias_lds[t] = bv;
  }
  __syncthreads();                             // only barrier in the kernel

  const int wv = threadIdx.x >> 6;
  const int l  = threadIdx.x & 63;
  const int e16 = l & 15, g = l >> 4;
  const int swz = (e16 & 7) << 3;
  const uint4* wlds4 = (const uint4*)wlds;
  u16* myhb = hb[wv];
  const int tStride = gridDim.x << 3;

  h8 tA0, tA1, tA2, tA3;  U16 wA0, wA1;
  h8 tB0, tB1, tB2, tB3;  U16 wB0, wB1;

  int t = blockIdx.x*8 + wv;                   // always < nTiles (2048 < 20000)
  K2_LOAD(tA0,tA1,tA2,tA3,wA0,wA1,t)
  while (true){
    int tn = t + tStride;
    bool v1 = tn < nTiles;
    if (v1) { K2_LOAD(tB0,tB1,tB2,tB3,wB0,wB1,tn) }
    K2_TILE(tA0,tA1,tA2,tA3,wA0,wA1,t)
    if (!v1) return;
    int tn2 = tn + tStride;
    bool v2 = tn2 < nTiles;
    if (v2) { K2_LOAD(tA0,tA1,tA2,tA3,wA0,wA1,tn2) }
    K2_TILE(tB0,tB1,tB2,tB3,wB0,wB1,tn)
    if (!v2) return;
    t = tn2;
  }
}

extern "C" void kernel_launch(void* const* d_in, const int* in_sizes, int n_in,
                              void* d_out, int out_size, void* d_ws, size_t ws_size,
                              hipStream_t stream) {
  const float* X   = (const float*)d_in[0];
  const float* T   = (const float*)d_in[1];
  const int*   EI  = (const int*)  d_in[2];
  const float* Wq  = (const float*)d_in[3];
  const float* Wk  = (const float*)d_in[4];
  const float* w1w = (const float*)d_in[5];
  const float* b1w = (const float*)d_in[6];
  const float* w2w = (const float*)d_in[7];
  const float* b2w = (const float*)d_in[8];
  const float* w1t = (const float*)d_in[9];
  const float* b1t = (const float*)d_in[10];
  const float* w2t = (const float*)d_in[11];
  const float* b2t = (const float*)d_in[12];
  float* out = (float*)d_out;

  u16* ws   = (u16*)d_ws;
  u16* pack = ws;                           // 240 KB packed weights
  u16* Q    = ws + 122880;                  // [N][256] f16 (10.24 MB)
  u16* Kv   = Q + (size_t)NN*256;           // [N][256] f16 (10.24 MB)
  u16* Wg   = Kv + (size_t)NN*256;          // [E][64] f16  (40.96 MB)

  k0_pack<<<64, 256, 0, stream>>>(Wq, Wk, w1w, w2w, w1t, w2t, pack);
  k1_proj<<<dim3((NN + 63)/64, 4), 256, 0, stream>>>(X, pack, Q, Kv);
  kA_dot<<<EE/64, 256, 0, stream>>>(Q, Kv, EI, Wg);
  k2_mlp<<<256, 512, 0, stream>>>(Wg, T, (const u16*)(ws + 65536),
      b1w, b2w, b1t, b2t, out, EE/16);
}